// Round 18
// baseline (158.794 us; speedup 1.0000x reference)
//
#include <hip/hip_runtime.h>
#include <math.h>

#define L_SEQ 16384
#define H_DIM 1024
#define P_DIM 512
#define N2P   1024
#define KDIM  1024
#define NKT   16     // KDIM / 64 K-tiles
#define CHUNK 64
#define NCHUNK 256   // L_SEQ / CHUNK

typedef __attribute__((ext_vector_type(8))) short short8;
typedef __attribute__((ext_vector_type(4))) float f32x4;
typedef __attribute__((address_space(3))) const char* lds3_t;

__device__ __forceinline__ unsigned short f2bf(float f){
    unsigned int u = __float_as_uint(f);
    u = (u + 0x7FFFu + ((u >> 16) & 1u)) >> 16;
    return (unsigned short)u;
}
__device__ __forceinline__ float bf2f(unsigned int lo16){
    return __uint_as_float(lo16 << 16);
}

// ---------------- prep: lambda, coef, λ^64, wtab[t][p]=λ^(63-t), wpow256[d][p]=λ^(256d)
__global__ void k_prep_lambda(const float* __restrict__ lre, const float* __restrict__ lim,
                              const float* __restrict__ lstep,
                              float* __restrict__ lam, float* __restrict__ coef,
                              float* __restrict__ lpow, float* __restrict__ wtab,
                              float* __restrict__ wpow256)
{
    int p = threadIdx.x;
    double step = exp((double)lstep[p]);
    double dr = (double)lre[p], di = (double)lim[p];
    double ar = dr*step, ai = di*step;
    double er = exp(ar);
    double lbr = er*cos(ai), lbi = er*sin(ai);
    lam[2*p] = (float)lbr; lam[2*p+1] = (float)lbi;
    double nr = lbr - 1.0, ni = lbi;
    double d2 = dr*dr + di*di;
    coef[2*p]   = (float)((nr*dr + ni*di)/d2);
    coef[2*p+1] = (float)((ni*dr - nr*di)/d2);
    double pwr = 1.0, pwi = 0.0;
    for (int tt = 63; tt >= 0; --tt){
        wtab[((size_t)tt*P_DIM + p)*2]     = (float)pwr;
        wtab[((size_t)tt*P_DIM + p)*2 + 1] = (float)pwi;
        double t2 = pwr*lbr - pwi*lbi;
        pwi = pwr*lbi + pwi*lbr;
        pwr = t2;
    }
    double xr = lbr, xi = lbi;
    #pragma unroll
    for (int s=0;s<6;s++){ double t = xr*xr - xi*xi; xi = 2.0*xr*xi; xr = t; } // λ^64
    lpow[2*p] = (float)xr; lpow[2*p+1] = (float)xi;
    double qr = xr, qi = xi;
    #pragma unroll
    for (int s=0;s<2;s++){ double t = qr*qr - qi*qi; qi = 2.0*qr*qi; qr = t; } // λ^256
    double wr_ = 1.0, wi_ = 0.0;
    for (int d=0; d<64; ++d){
        wpow256[((size_t)d*P_DIM + p)*2]     = (float)wr_;
        wpow256[((size_t)d*P_DIM + p)*2 + 1] = (float)wi_;
        double t2 = wr_*qr - wi_*qi;
        wi_ = wr_*qi + wi_*qr;
        wr_ = t2;
    }
}

// merged BB + CC + u-cast
__global__ __launch_bounds__(256)
void k_prep_misc(const float* __restrict__ B, const float* __restrict__ C,
                 const float* __restrict__ coef,
                 unsigned short* __restrict__ BB, unsigned short* __restrict__ CC,
                 const float4* __restrict__ u, unsigned short* __restrict__ u16)
{
    int bid = blockIdx.x;
    if (bid < 2048){
        int i = bid*256 + threadIdx.x;   // i = p*H + h
        int p = i >> 10, h = i & 1023;
        float br = B[2*i], bi = B[2*i+1];
        float cr = coef[2*p], ci = coef[2*p+1];
        BB[(size_t)(2*p)*H_DIM + h]   = f2bf(cr*br - ci*bi);
        BB[(size_t)(2*p+1)*H_DIM + h] = f2bf(cr*bi + ci*br);
    } else if (bid < 4096){
        int i = (bid-2048)*256 + threadIdx.x;   // i = h*P + p
        int h = i >> 9, p = i & 511;
        float cr = C[2*i], ci = C[2*i+1];
        CC[(size_t)h*N2P + 2*p]     = f2bf(2.f*cr);
        CC[(size_t)h*N2P + 2*p + 1] = f2bf(-2.f*ci);
    } else {
        int i = (bid-4096)*256 + threadIdx.x;
        float4 a = u[2*i], b = u[2*i+1];
        union { short8 v; unsigned short s[8]; } r;
        r.s[0]=f2bf(a.x); r.s[1]=f2bf(a.y); r.s[2]=f2bf(a.z); r.s[3]=f2bf(a.w);
        r.s[4]=f2bf(b.x); r.s[5]=f2bf(b.y); r.s[6]=f2bf(b.z); r.s[7]=f2bf(b.w);
        *reinterpret_cast<short8*>(u16 + (size_t)i*8) = r.v;
    }
}

// ---------------- GEMM: R17 K-loop (single barrier/KT), new fused-scan epilogue ----
// EPI=0 (gemm1): NO C-write. Epilogue: per-chunk aggs (LDS) -> publish block agg
//   (atomics+fence+flag) -> weighted-sum lookback -> per-chunk xinit -> 4-pass LDS
//   transpose of acc -> 64-step recurrence per (p,chunk) -> emit bf16 xs16.
// EPI=1 (gemm2): fp32 out to Cf += Dv[col]*bf16(U16).
template<int EPI>
__global__ __launch_bounds__(512, 2)
void gemm256(const unsigned short* __restrict__ A, const unsigned short* __restrict__ Bm,
             float* __restrict__ Cf, const float* __restrict__ Dv,
             const unsigned short* __restrict__ U16,
             const float* __restrict__ wtab, const float* __restrict__ wpow256,
             const float* __restrict__ lam, const float* __restrict__ lpow,
             unsigned long long* __restrict__ aggBlkG, unsigned int* __restrict__ flagG,
             unsigned short* __restrict__ xs16O)
{
    __shared__ char lds[131072];
    const int tid  = threadIdx.x;
    const int lane = tid & 63;
    const int wid  = tid >> 6;
    const int wm = wid >> 2, wn = wid & 3;          // 2(M) x 4(N) waves
    const int wg = ((int)blockIdx.x & 7) * 32 + ((int)blockIdx.x >> 3);  // XCD swizzle
    const int tm = wg >> 2, tn = wg & 3;
    const int lr = lane & 15;

    const int scol = ((tid & 7) ^ ((tid >> 3) & 7)) << 3;   // ushort units, pre-swizzled
    const int srow = tid >> 3;                               // 0..63
    const int kc0 = (((lane >> 4)      ^ (lr & 7)) << 4);
    const int kc1 = ((((lane >> 4) | 4) ^ (lr & 7)) << 4);
    const int aSub = wm*16384 + lr*128;
    const int bSub = 32768 + (wn >> 1)*16384 + (wn & 1)*8192 + lr*128;

#define GLOAD(SRC, DST) __builtin_amdgcn_global_load_lds( \
        (const __attribute__((address_space(1))) void*)(SRC), \
        (__attribute__((address_space(3))) void*)(DST), 16, 0, 0)
#define STAGE_A(src_, par_, h_) do{ \
    char* d_ = lds + ((par_)<<16) + (h_)*16384 + tid*16; \
    const unsigned short* s_ = A + (size_t)(tm*256 + (h_)*128 + srow)*KDIM + (size_t)(src_)*64 + scol; \
    GLOAD(s_, d_); GLOAD(s_ + (size_t)64*KDIM, d_ + 8192); }while(0)
#define STAGE_B(src_, par_, h_) do{ \
    char* d_ = lds + ((par_)<<16) + 32768 + (h_)*16384 + tid*16; \
    const unsigned short* s_ = Bm + (size_t)(tn*256 + (h_)*128 + srow)*KDIM + (size_t)(src_)*64 + scol; \
    GLOAD(s_, d_); GLOAD(s_ + (size_t)64*KDIM, d_ + 8192); }while(0)
#define DSR(D, P, IMM) asm volatile("ds_read_b128 %0, %1 offset:" IMM : "=v"(D) : "v"(P))
#define LGKM(N) do{ asm volatile("s_waitcnt lgkmcnt(" #N ")" ::: "memory"); \
                    __builtin_amdgcn_sched_barrier(0); }while(0)
#define VMC0  asm volatile("s_waitcnt vmcnt(0)" ::: "memory")
#define ABAR  asm volatile("s_barrier" ::: "memory")
#define SB0   __builtin_amdgcn_sched_barrier(0)
#define MFMA(a,b,c) __builtin_amdgcn_mfma_f32_16x16x32_bf16(a,b,c,0,0,0)
#define PRIO1 __builtin_amdgcn_s_setprio(1)
#define PRIO0 __builtin_amdgcn_s_setprio(0)

    short8 a1[4], a2[4], bb0[4], bb1[4];
    f32x4 acc[8][4];
    #pragma unroll
    for (int m=0;m<8;m++)
        #pragma unroll
        for (int n=0;n<4;n++) acc[m][n] = (f32x4){0.f,0.f,0.f,0.f};

    STAGE_A(0,0,0); STAGE_A(0,0,1); STAGE_B(0,0,0); STAGE_B(0,0,1);
    VMC0; ABAR;

    #pragma unroll 2
    for (int kt = 0; kt < NKT; ++kt) {
        const int sb   = (kt & 1) << 16;
        const int dpar = (~kt) & 1;
        const int src  = (kt+1 < NKT) ? kt+1 : NKT-1;
        lds3_t pa0 = (lds3_t)(lds + sb + aSub + kc0);
        lds3_t pa1 = (lds3_t)(lds + sb + aSub + kc1);
        lds3_t pb0 = (lds3_t)(lds + sb + bSub + kc0);
        lds3_t pb1 = (lds3_t)(lds + sb + bSub + kc1);

        DSR(a1[0], pa0, "0");    DSR(a1[1], pa0, "2048");
        DSR(a1[2], pa0, "4096"); DSR(a1[3], pa0, "6144");
        DSR(bb0[0], pb0, "0");    DSR(bb0[1], pb0, "2048");
        DSR(bb0[2], pb0, "4096"); DSR(bb0[3], pb0, "6144");
        STAGE_A(src, dpar, 0); STAGE_A(src, dpar, 1);
        DSR(a2[0], pa0, "8192");  DSR(a2[1], pa0, "10240");
        DSR(a2[2], pa0, "12288"); DSR(a2[3], pa0, "14336");
        LGKM(4);
        PRIO1;
        #pragma unroll
        for (int m=0;m<4;m++)
            #pragma unroll
            for (int n=0;n<4;n++) acc[m][n] = MFMA(a1[m], bb0[n], acc[m][n]);
        PRIO0; SB0;
        DSR(a1[0], pa1, "0");    DSR(a1[1], pa1, "2048");
        DSR(a1[2], pa1, "4096"); DSR(a1[3], pa1, "6144");
        DSR(bb1[0], pb1, "0");    DSR(bb1[1], pb1, "2048");
        DSR(bb1[2], pb1, "4096"); DSR(bb1[3], pb1, "6144");
        STAGE_B(src, dpar, 0); STAGE_B(src, dpar, 1);
        LGKM(8);
        PRIO1;
        #pragma unroll
        for (int m=0;m<4;m++)
            #pragma unroll
            for (int n=0;n<4;n++) acc[4+m][n] = MFMA(a2[m], bb0[n], acc[4+m][n]);
        PRIO0; SB0;
        DSR(a2[0], pa1, "8192");  DSR(a2[1], pa1, "10240");
        DSR(a2[2], pa1, "12288"); DSR(a2[3], pa1, "14336");
        LGKM(4);
        PRIO1;
        #pragma unroll
        for (int m=0;m<4;m++)
            #pragma unroll
            for (int n=0;n<4;n++) acc[m][n] = MFMA(a1[m], bb1[n], acc[m][n]);
        PRIO0; SB0;
        LGKM(0);
        PRIO1;
        #pragma unroll
        for (int m=0;m<4;m++)
            #pragma unroll
            for (int n=0;n<4;n++) acc[4+m][n] = MFMA(a2[m], bb1[n], acc[4+m][n]);
        PRIO0; SB0;
        VMC0;
        ABAR;
    }

    if (!EPI){
        // ---------------- fused scan epilogue (K-loop data in LDS now dead) -------
        float* aggL = (float*)lds;              // [4][128][2]  4KB
        float* xinL = (float*)(lds + 4096);     // [4][128][2]  4KB
        float* plnR = (float*)(lds + 8192);     // [64][129] f32 (33024 B)
        float* plnI = (float*)(lds + 8192 + 33024);
        // (a) per-chunk aggregates -> LDS
        {
            const int q = lane >> 4;
            #pragma unroll
            for (int n=0;n<4;n++){
                const int pb = wn*32 + n*8 + (lr >> 1);
                const int pg = tn*128 + pb;
                float wr[16], wi[16];
                #pragma unroll
                for (int mm=0;mm<4;mm++)
                    #pragma unroll
                    for (int j=0;j<4;j++){
                        const float* wp = wtab + ((size_t)(mm*16 + q*4 + j)*P_DIM + pg)*2;
                        wr[mm*4+j] = wp[0]; wi[mm*4+j] = wp[1];
                    }
                #pragma unroll
                for (int h=0; h<2; h++){
                    float s1 = 0.f, s2 = 0.f;
                    #pragma unroll
                    for (int mm=0;mm<4;mm++)
                        #pragma unroll
                        for (int j=0;j<4;j++){
                            float x = acc[h*4+mm][n][j];
                            s1 += wr[mm*4+j]*x;
                            s2 += wi[mm*4+j]*x;
                        }
                    s1 += __shfl_xor(s1,16); s1 += __shfl_xor(s1,32);
                    s2 += __shfl_xor(s2,16); s2 += __shfl_xor(s2,32);
                    float s1p = __shfl_xor(s1,1);
                    float s2p = __shfl_xor(s2,1);
                    if (lane < 16 && !(lr & 1)){
                        int cloc = 2*wm + h;
                        aggL[(cloc*128 + pb)*2]     = s1 - s2p;
                        aggL[(cloc*128 + pb)*2 + 1] = s2 + s1p;
                    }
                }
            }
        }
        asm volatile("s_waitcnt lgkmcnt(0)" ::: "memory");
        ABAR;
        // (b) publish block aggregate (device-scope atomics), then flag
        if (tid < 128){
            int p = tid, pg = tn*128 + p;
            float l64r = lpow[2*pg], l64i = lpow[2*pg+1];
            float br = aggL[p*2], bi = aggL[p*2+1];
            #pragma unroll
            for (int c=1;c<4;c++){
                float t_ = br*l64r - bi*l64i + aggL[(c*128+p)*2];
                bi       = br*l64i + bi*l64r + aggL[(c*128+p)*2+1];
                br = t_;
            }
            unsigned long long pk =
                ((unsigned long long)__float_as_uint(bi) << 32) | __float_as_uint(br);
            atomicExch(&aggBlkG[((size_t)tn*64 + tm)*128 + p], pk);
        }
        VMC0; ABAR;
        if (tid == 0){
            __threadfence();
            atomicExch(&flagG[tn*64 + tm], 1u);
        }
        // (c) lookback: exclusive prefix as a weighted sum (order-free, parallel reads)
        float Xr = 0.f, Xi = 0.f;
        if (tid < 128 && tm > 0){
            int p = tid, pg = tn*128 + p;
            for (int k=0; k<tm; ++k){
                int guard = 0;
                while (atomicAdd(&flagG[tn*64 + k], 0u) == 0u)
                    if (++guard > (1<<24)) break;   // defensive: no hang
            }
            __threadfence();
            const unsigned long long* ab = aggBlkG + (size_t)tn*64*128;
            for (int k=0; k<tm; ++k){
                unsigned long long pk = ab[(size_t)k*128 + p];
                float br = __uint_as_float((unsigned)pk);
                float bi = __uint_as_float((unsigned)(pk >> 32));
                const float* wp = wpow256 + ((size_t)(tm-1-k)*P_DIM + pg)*2;
                Xr += wp[0]*br - wp[1]*bi;
                Xi += wp[0]*bi + wp[1]*br;
            }
        }
        // (d) per-chunk xinit -> LDS
        if (tid < 128){
            int p = tid, pg = tn*128 + p;
            float l64r = lpow[2*pg], l64i = lpow[2*pg+1];
            float xr_ = Xr, xi_ = Xi;
            xinL[p*2] = xr_; xinL[p*2+1] = xi_;
            #pragma unroll
            for (int c=1;c<4;c++){
                float t_ = xr_*l64r - xi_*l64i + aggL[((c-1)*128+p)*2];
                xi_      = xr_*l64i + xi_*l64r + aggL[((c-1)*128+p)*2+1];
                xr_ = t_;
                xinL[(c*128+p)*2] = xr_; xinL[(c*128+p)*2+1] = xi_;
            }
        }
        // (e) 4 transpose-scan passes: (wm-half h) x (p-half ph)
        unsigned int* xsO = (unsigned int*)xs16O;
        #pragma unroll 1
        for (int h=0; h<2; ++h){
            #pragma unroll 1
            for (int ph=0; ph<2; ++ph){
                asm volatile("s_waitcnt lgkmcnt(0)" ::: "memory");
                ABAR;
                if (wm == h && (wn >> 1) == ph){
                    const int ppb = (wn & 1)*32 + (lr >> 1);
                    float* pl = (lr & 1) ? plnI : plnR;
                    #pragma unroll
                    for (int m=0;m<8;m++){
                        const int rw = m*16 + (lane>>4)*4;
                        #pragma unroll
                        for (int n=0;n<4;n++){
                            float* d = pl + (ppb + n*8)*129 + rw;
                            d[0]=acc[m][n][0]; d[1]=acc[m][n][1];
                            d[2]=acc[m][n][2]; d[3]=acc[m][n][3];
                        }
                    }
                }
                asm volatile("s_waitcnt lgkmcnt(0)" ::: "memory");
                ABAR;
                if (tid < 128){
                    const int pp = tid & 63, cc = tid >> 6;
                    const int pg = tn*128 + ph*64 + pp;
                    const float lrr = lam[2*pg], lii = lam[2*pg+1];
                    const int cloc = 2*h + cc;
                    float xr_ = xinL[(cloc*128 + ph*64 + pp)*2];
                    float xi_ = xinL[(cloc*128 + ph*64 + pp)*2 + 1];
                    const float* pre = plnR + pp*129 + cc*64;
                    const float* pim = plnI + pp*129 + cc*64;
                    unsigned int* o = xsO + (size_t)(tm*256 + h*128 + cc*64)*512 + pg;
                    #pragma unroll 8
                    for (int t=0;t<64;t++){
                        float t_ = xr_*lrr - xi_*lii + pre[t];
                        xi_      = xr_*lii + xi_*lrr + pim[t];
                        xr_ = t_;
                        o[(size_t)t*512] = (unsigned)f2bf(xr_) | ((unsigned)f2bf(xi_) << 16);
                    }
                }
            }
        }
    } else {
        const int orow0 = tm*256 + wm*128 + (lane>>4)*4;
        const int ocol0 = tn*256 + wn*64 + lr;
        #pragma unroll
        for (int m=0;m<8;m++){
            #pragma unroll
            for (int n=0;n<4;n++){
                int row = orow0 + m*16, col = ocol0 + n*16;
                #pragma unroll
                for (int j=0;j<4;j++){
                    size_t idx = (size_t)(row + j)*N2P + col;
                    Cf[idx] = acc[m][n][j] + Dv[col]*bf2f(U16[idx]);
                }
            }
        }
    }
#undef GLOAD
#undef STAGE_A
#undef STAGE_B
#undef DSR
#undef LGKM
#undef VMC0
#undef ABAR
#undef SB0
#undef MFMA
#undef PRIO1
#undef PRIO0
}

extern "C" void kernel_launch(void* const* d_in, const int* in_sizes, int n_in,
                              void* d_out, int out_size, void* d_ws, size_t ws_size,
                              hipStream_t stream)
{
    const float* u   = (const float*)d_in[0];
    const float* lre = (const float*)d_in[1];
    const float* lim = (const float*)d_in[2];
    const float* B   = (const float*)d_in[3];
    const float* C   = (const float*)d_in[4];
    const float* D   = (const float*)d_in[5];
    const float* ls  = (const float*)d_in[6];
    float* out = (float*)d_out;

    char* w = (char*)d_ws;
    unsigned short* u16  = (unsigned short*)(w + 0);          // 32 MiB
    unsigned short* xs16 = (unsigned short*)(w + 33554432);   // 32 MiB
    unsigned short* BB   = (unsigned short*)(w + 67108864);   // 2 MiB
    unsigned short* CC   = (unsigned short*)(w + 69206016);   // 2 MiB
    float* lam     = (float*)(w + 71303168);                  // 4 KiB
    float* coef    = (float*)(w + 71307264);                  // 4 KiB
    float* lpow    = (float*)(w + 71311360);                  // 4 KiB
    float* wtab    = (float*)(w + 71315456);                  // 256 KiB
    float* wpow256 = (float*)(w + 71577600);                  // 256 KiB
    unsigned long long* aggBlk = (unsigned long long*)(w + 71839744);  // 256 KiB
    unsigned int* flags = (unsigned int*)(w + 72101888);      // 1 KiB

    hipMemsetAsync(flags, 0, 1024, stream);
    k_prep_lambda<<<1, P_DIM, 0, stream>>>(lre, lim, ls, lam, coef, lpow, wtab, wpow256);
    k_prep_misc<<<12288, 256, 0, stream>>>(B, C, coef, BB, CC, (const float4*)u, u16);

    // gemm1: fused Bu-GEMM + chunk aggs + cross-block scan + xs16 emit (no C write)
    gemm256<0><<<256, 512, 0, stream>>>(u16, BB, nullptr, nullptr, nullptr,
                                        wtab, wpow256, lam, lpow, aggBlk, flags, xs16);

    // gemm2: out = xs16 @ CC^T + D*u
    gemm256<1><<<256, 512, 0, stream>>>(xs16, CC, out, D, u16,
                                        nullptr, nullptr, nullptr, nullptr,
                                        nullptr, nullptr, nullptr);
}